// Round 6
// baseline (152.072 us; speedup 1.0000x reference)
//
#include <hip/hip_runtime.h>
#include <hip/hip_cooperative_groups.h>
#include <math.h>

namespace cg = cooperative_groups;

namespace {
constexpr int L = 7, S = 200, SE = 240, D = 32, B = 512;
constexpr int NTOK = L * B;      // 3584
constexpr int NCLUST = L * S;    // 1400
constexpr int GRID = 1024;       // 4 blocks/CU * 256 CU, all co-resident (cooperative)
constexpr int NWAVES = GRID * 4; // 4096
constexpr int NROUTE_WAVES = NWAVES - NCLUST;   // 2696 router waves
constexpr int NTOK2 = NTOK - NROUTE_WAVES;      // 888 waves route a 2nd token

// ---- router phase A: dots vs 200 centroids, exact top-3 (jax tie-break), softmax ----
// Writes (idx, p) to ws. Reads only x, vc — independent of compose.
__device__ __forceinline__ void route_phaseA(
    const int tok, const int lane,
    const float* __restrict__ x, const float* __restrict__ vc,
    int4* __restrict__ tki, float4* __restrict__ tkp)
{
  const int l = tok >> 9;  // B = 512
  const int q = lane & 7;  // float4 column
  const int r8 = lane >> 3;

  const float4 xq = reinterpret_cast<const float4*>(x + tok * D)[q];
  const float* vcl = vc + l * S * D;

  float v0 = -INFINITY, v1 = -INFINITY, v2 = -INFINITY;
  int i0 = 0x7fffffff, i1 = 0x7fffffff, i2 = 0x7fffffff;
  for (int s0 = 0; s0 < S; s0 += 8) {  // 25 iters; wave reads 8 rows x 128B contiguous
    const int row = s0 + r8;
    const float4 v = reinterpret_cast<const float4*>(vcl + row * D)[q];
    float part = v.x * xq.x + v.y * xq.y + v.z * xq.z + v.w * xq.w;
    part += __shfl_xor(part, 1);
    part += __shfl_xor(part, 2);
    part += __shfl_xor(part, 4);
    if (q == 0) {  // strict > keeps earlier (smaller) index; row increases per lane
      if (part > v0) { v2 = v1; i2 = i1; v1 = v0; i1 = i0; v0 = part; i0 = row; }
      else if (part > v1) { v2 = v1; i2 = i1; v1 = part; i1 = row; }
      else if (part > v2) { v2 = part; i2 = row; }
    }
  }
#pragma unroll
  for (int m = 1; m < 64; m <<= 1) {  // butterfly merge (desc value, low index on ties)
    const float u0 = __shfl_xor(v0, m);
    const float u1 = __shfl_xor(v1, m);
    const float u2 = __shfl_xor(v2, m);
    const int j0 = __shfl_xor(i0, m);
    const int j1 = __shfl_xor(i1, m);
    const int j2 = __shfl_xor(i2, m);
#pragma unroll
    for (int t = 0; t < 3; ++t) {
      const float u = (t == 0) ? u0 : (t == 1) ? u1 : u2;
      const int j = (t == 0) ? j0 : (t == 1) ? j1 : j2;
      const bool b0 = (u > v0) || (u == v0 && j < i0);
      const bool b1 = (u > v1) || (u == v1 && j < i1);
      const bool b2 = (u > v2) || (u == v2 && j < i2);
      if (b0) { v2 = v1; i2 = i1; v1 = v0; i1 = i0; v0 = u; i0 = j; }
      else if (b1) { v2 = v1; i2 = i1; v1 = u; i1 = j; }
      else if (b2) { v2 = u; i2 = j; }
    }
  }
  if (lane == 0) {
    const float e1 = __expf(v1 - v0);
    const float e2 = __expf(v2 - v0);
    const float inv = 1.f / (1.f + e1 + e2);
    tki[tok] = make_int4(i0, i1, i2, 0);
    tkp[tok] = make_float4(inv, e1 * inv, e2 * inv, 0.f);
  }
}

// ---- cooperative fused kernel: compose || route-A, grid.sync, gather ----
// Blocks 0..349: pure compose (wave-per-cluster). Blocks 350..1023: pure route.
// One grid-wide barrier replaces flags/spinning (R3/R5's failure mode).
__global__ __launch_bounds__(256, 4) void coop_kernel(
    const float* __restrict__ x,     // [L,B,D]
    const float* __restrict__ vc,    // [L,S,D]
    const float* __restrict__ vec,   // [L,S,SE,D]
    const float* __restrict__ gain,  // [L,S,SE,2]
    const int* __restrict__ blk,     // [L,S,SE,2]
    float* __restrict__ C,           // [L*S, D] ws
    int4* __restrict__ tki,          // [NTOK] ws
    float4* __restrict__ tkp,        // [NTOK] ws
    float* __restrict__ out)         // [L,B,D]
{
  const int wave = threadIdx.x >> 6;
  const int lane = threadIdx.x & 63;
  const int W = blockIdx.x * 4 + wave;  // global wave id [0, 4096)

  if (W < NCLUST) {
    // ---------------- compose: one wave per (l,s) ----------------
    __shared__ float wl[4][SE];
    const int ls = W;
    for (int e = lane; e < SE; e += 64) {
      const float2 g2 = reinterpret_cast<const float2*>(gain)[ls * SE + e];
      const int2 b2 = reinterpret_cast<const int2*>(blk)[ls * SE + e];
      wl[wave][e] = (b2.x != 0) ? 1.0f / (1.0f + __expf(-g2.x)) : 0.0f;
    }
    __syncthreads();  // compose blocks are uniform (blocks 0..349), safe
    const int d4 = lane & 7;   // float4 column [0,8)
    const int eg = lane >> 3;  // e-row group [0,8)
    const float4* v4 = reinterpret_cast<const float4*>(vec) + (size_t)ls * SE * 8;
    float4 acc = make_float4(0.f, 0.f, 0.f, 0.f);
#pragma unroll 10
    for (int k = 0; k < 30; ++k) {  // wave reads 8 rows x 128B = 1KB contiguous per step
      const int e = eg + 8 * k;
      const float we = wl[wave][e];
      const float4 v = v4[e * 8 + d4];
      acc.x += we * v.x; acc.y += we * v.y; acc.z += we * v.z; acc.w += we * v.w;
    }
#pragma unroll
    for (int m = 8; m < 64; m <<= 1) {  // reduce over eg (lane bits 3..5)
      acc.x += __shfl_xor(acc.x, m);
      acc.y += __shfl_xor(acc.y, m);
      acc.z += __shfl_xor(acc.z, m);
      acc.w += __shfl_xor(acc.w, m);
    }
    if (eg == 0) reinterpret_cast<float4*>(C + ls * D)[d4] = acc;
  } else {
    // ---------------- route phase A: 1-2 tokens per wave ----------------
    const int g = W - NCLUST;  // [0, 2696)
    route_phaseA(g, lane, x, vc, tki, tkp);
    if (g < NTOK2) route_phaseA(g + NROUTE_WAVES, lane, x, vc, tki, tkp);
  }

  cg::this_grid().sync();  // platform barrier: visibility of C, tki, tkp

  // ---------------- gather: wave W -> token W ----------------
  if (W < NTOK) {
    const int l = W >> 9;
    const int4 id = tki[W];    // same addr across lanes -> broadcast load
    const float4 p = tkp[W];
    if (lane < D) {
      const float* Cl = C + l * S * D;
      out[W * D + lane] = p.x * Cl[id.x * D + lane] +
                          p.y * Cl[id.y * D + lane] +
                          p.z * Cl[id.z * D + lane];
    }
  }
}

// ---------------- fallback (proven R4 path): compose, then route+gather ----------------
__global__ __launch_bounds__(256) void compose_kernel(
    const float* __restrict__ vec, const float* __restrict__ gain,
    const int* __restrict__ blk, float* __restrict__ C)
{
  const int wave = threadIdx.x >> 6;
  const int lane = threadIdx.x & 63;
  __shared__ float wl[4][SE];
  const int ls = blockIdx.x * 4 + wave;
  for (int e = lane; e < SE; e += 64) {
    const float2 g2 = reinterpret_cast<const float2*>(gain)[ls * SE + e];
    const int2 b2 = reinterpret_cast<const int2*>(blk)[ls * SE + e];
    wl[wave][e] = (b2.x != 0) ? 1.0f / (1.0f + __expf(-g2.x)) : 0.0f;
  }
  __syncthreads();
  const int d4 = lane & 7;
  const int eg = lane >> 3;
  const float4* v4 = reinterpret_cast<const float4*>(vec) + (size_t)ls * SE * 8;
  float4 acc = make_float4(0.f, 0.f, 0.f, 0.f);
#pragma unroll 10
  for (int k = 0; k < 30; ++k) {
    const int e = eg + 8 * k;
    const float we = wl[wave][e];
    const float4 v = v4[e * 8 + d4];
    acc.x += we * v.x; acc.y += we * v.y; acc.z += we * v.z; acc.w += we * v.w;
  }
#pragma unroll
  for (int m = 8; m < 64; m <<= 1) {
    acc.x += __shfl_xor(acc.x, m);
    acc.y += __shfl_xor(acc.y, m);
    acc.z += __shfl_xor(acc.z, m);
    acc.w += __shfl_xor(acc.w, m);
  }
  if (eg == 0) reinterpret_cast<float4*>(C + ls * D)[d4] = acc;
}

__global__ __launch_bounds__(256) void route_kernel(
    const float* __restrict__ x, const float* __restrict__ vc,
    const float* __restrict__ C, float* __restrict__ out)
{
  const int wave = threadIdx.x >> 6;
  const int lane = threadIdx.x & 63;
  const int tok = blockIdx.x * 4 + wave;
  const int l = tok >> 9;
  const int q = lane & 7;
  const int r8 = lane >> 3;
  const float4 xq = reinterpret_cast<const float4*>(x + tok * D)[q];
  const float* vcl = vc + l * S * D;
  float v0 = -INFINITY, v1 = -INFINITY, v2 = -INFINITY;
  int i0 = 0x7fffffff, i1 = 0x7fffffff, i2 = 0x7fffffff;
  for (int s0 = 0; s0 < S; s0 += 8) {
    const int row = s0 + r8;
    const float4 v = reinterpret_cast<const float4*>(vcl + row * D)[q];
    float part = v.x * xq.x + v.y * xq.y + v.z * xq.z + v.w * xq.w;
    part += __shfl_xor(part, 1);
    part += __shfl_xor(part, 2);
    part += __shfl_xor(part, 4);
    if (q == 0) {
      if (part > v0) { v2 = v1; i2 = i1; v1 = v0; i1 = i0; v0 = part; i0 = row; }
      else if (part > v1) { v2 = v1; i2 = i1; v1 = part; i1 = row; }
      else if (part > v2) { v2 = part; i2 = row; }
    }
  }
#pragma unroll
  for (int m = 1; m < 64; m <<= 1) {
    const float u0 = __shfl_xor(v0, m);
    const float u1 = __shfl_xor(v1, m);
    const float u2 = __shfl_xor(v2, m);
    const int j0 = __shfl_xor(i0, m);
    const int j1 = __shfl_xor(i1, m);
    const int j2 = __shfl_xor(i2, m);
#pragma unroll
    for (int t = 0; t < 3; ++t) {
      const float u = (t == 0) ? u0 : (t == 1) ? u1 : u2;
      const int j = (t == 0) ? j0 : (t == 1) ? j1 : j2;
      const bool b0 = (u > v0) || (u == v0 && j < i0);
      const bool b1 = (u > v1) || (u == v1 && j < i1);
      const bool b2 = (u > v2) || (u == v2 && j < i2);
      if (b0) { v2 = v1; i2 = i1; v1 = v0; i1 = i0; v0 = u; i0 = j; }
      else if (b1) { v2 = v1; i2 = i1; v1 = u; i1 = j; }
      else if (b2) { v2 = u; i2 = j; }
    }
  }
  const float e1 = __expf(v1 - v0);
  const float e2 = __expf(v2 - v0);
  const float inv = 1.f / (1.f + e1 + e2);
  if (lane < D) {
    const float* Cl = C + l * S * D;
    out[tok * D + lane] = inv * Cl[i0 * D + lane] +
                          e1 * inv * Cl[i1 * D + lane] +
                          e2 * inv * Cl[i2 * D + lane];
  }
}

}  // namespace

extern "C" void kernel_launch(void* const* d_in, const int* in_sizes, int n_in,
                              void* d_out, int out_size, void* d_ws, size_t ws_size,
                              hipStream_t stream) {
  const float* x = (const float*)d_in[0];      // [L,B,D]
  const float* vc = (const float*)d_in[1];     // [L,S,D]
  const float* vec = (const float*)d_in[2];    // [L,S,SE,D]
  const float* gain = (const float*)d_in[3];   // [L,S,SE,2]
  const int* blk = (const int*)d_in[4];        // [L,S,SE,2]
  float* out = (float*)d_out;                  // [L,B,D]

  char* ws = (char*)d_ws;
  float* C = (float*)ws;                        // 179,200 B
  int4* tki = (int4*)(ws + 179200);             // 57,344 B
  float4* tkp = (float4*)(ws + 179200 + 57344); // 57,344 B

  void* args[] = {(void*)&x, (void*)&vc, (void*)&vec, (void*)&gain, (void*)&blk,
                  (void*)&C, (void*)&tki, (void*)&tkp, (void*)&out};
  const hipError_t err = hipLaunchCooperativeKernel(
      (const void*)coop_kernel, dim3(GRID), dim3(256), args, 0, stream);
  if (err != hipSuccess) {
    // fallback: proven spin-free two-dispatch path (~30 us)
    compose_kernel<<<NCLUST / 4, 256, 0, stream>>>(vec, gain, blk, C);
    route_kernel<<<NTOK / 4, 256, 0, stream>>>(x, vc, C, out);
  }
}

// Round 7
// 68.585 us; speedup vs baseline: 2.2173x; 2.2173x over previous
//
#include <hip/hip_runtime.h>
#include <math.h>

namespace {
constexpr int L = 7, S = 200, SE = 240, D = 32, B = 512;
constexpr int NTOK = L * B;      // 3584
constexpr int NCLUST = L * S;    // 1400

// ---------- kernel 1: compose. One WAVE per cluster, 1400 one-wave blocks. ----------
// C[ls,d] = sum_e sigmoid(gain[ls,e,0]) * (blk[ls,e,0]!=0) * vec[ls,e,d]
// 1400 blocks / 256 CUs = 5.47 blocks/CU, balanced; no LDS tree, shfl-only reduce.
__global__ __launch_bounds__(64) void compose_kernel(
    const float* __restrict__ vec,   // [L,S,SE,D]
    const float* __restrict__ gain,  // [L,S,SE,2]
    const int* __restrict__ blk,     // [L,S,SE,2]
    float* __restrict__ C)           // [L*S, D]
{
  const int ls = blockIdx.x;
  const int lane = threadIdx.x;
  __shared__ float sw[SE];
  for (int e = lane; e < SE; e += 64) {
    const float2 g2 = reinterpret_cast<const float2*>(gain)[ls * SE + e];  // 8B contiguous
    const int2 b2 = reinterpret_cast<const int2*>(blk)[ls * SE + e];
    sw[e] = (b2.x != 0) ? 1.0f / (1.0f + __expf(-g2.x)) : 0.0f;
  }
  __syncthreads();  // single-wave block: compiles to a waitcnt, no real barrier cost
  const int d4 = lane & 7;   // float4 column [0,8)
  const int eg = lane >> 3;  // e-row group [0,8)
  const float4* v4 = reinterpret_cast<const float4*>(vec) + (size_t)ls * SE * 8;
  float4 acc = make_float4(0.f, 0.f, 0.f, 0.f);
#pragma unroll 10
  for (int k = 0; k < 30; ++k) {  // wave reads 8 rows x 128B = 1KB contiguous per step
    const int e = eg + 8 * k;
    const float we = sw[e];
    const float4 v = v4[e * 8 + d4];
    acc.x += we * v.x; acc.y += we * v.y; acc.z += we * v.z; acc.w += we * v.w;
  }
#pragma unroll
  for (int m = 8; m < 64; m <<= 1) {  // reduce over eg (lane bits 3..5)
    acc.x += __shfl_xor(acc.x, m);
    acc.y += __shfl_xor(acc.y, m);
    acc.z += __shfl_xor(acc.z, m);
    acc.w += __shfl_xor(acc.w, m);
  }
  if (eg == 0) reinterpret_cast<float4*>(C + ls * D)[d4] = acc;
}

// ---------- kernel 2: route + gather. One wave per 4 tokens (same layer). ----------
// Batching 4 tokens amortizes the vc stream 4x (92MB -> 23MB of L2 reads).
// Dot layout per token: 64 lanes = 8 rows (r8) x 8 float4-cols (q); 3-shfl reduce
// leaves full dot on every lane of the octet; q==0 lanes run the top-3 chain.
__global__ __launch_bounds__(256) void route_kernel(
    const float* __restrict__ x,   // [L,B,D]
    const float* __restrict__ vc,  // [L,S,D]
    const float* __restrict__ C,   // [L*S, D]
    float* __restrict__ out)       // [L,B,D]
{
  const int wave = threadIdx.x >> 6;
  const int lane = threadIdx.x & 63;
  const int t0 = (blockIdx.x * 4 + wave) * 4;  // 4 consecutive tokens; 4 | 512 -> same layer
  const int l = t0 >> 9;                       // B = 512
  const int q = lane & 7;
  const int r8 = lane >> 3;

  float4 xq[4];
#pragma unroll
  for (int j = 0; j < 4; ++j)
    xq[j] = reinterpret_cast<const float4*>(x + (t0 + j) * D)[q];
  const float* vcl = vc + l * S * D;

  float v0[4], v1[4], v2[4];
  int i0[4], i1[4], i2[4];
#pragma unroll
  for (int j = 0; j < 4; ++j) {
    v0[j] = v1[j] = v2[j] = -INFINITY;
    i0[j] = i1[j] = i2[j] = 0x7fffffff;
  }

  for (int s0 = 0; s0 < S; s0 += 8) {  // 25 chunks; wave reads 8 rows x 128B contiguous
    const int row = s0 + r8;
    const float4 v = reinterpret_cast<const float4*>(vcl + row * D)[q];
#pragma unroll
    for (int j = 0; j < 4; ++j) {
      float part = v.x * xq[j].x + v.y * xq[j].y + v.z * xq[j].z + v.w * xq[j].w;
      part += __shfl_xor(part, 1);
      part += __shfl_xor(part, 2);
      part += __shfl_xor(part, 4);
      if (q == 0) {  // strict > keeps earlier (smaller) index; row increases per lane
        if (part > v0[j]) { v2[j] = v1[j]; i2[j] = i1[j]; v1[j] = v0[j]; i1[j] = i0[j]; v0[j] = part; i0[j] = row; }
        else if (part > v1[j]) { v2[j] = v1[j]; i2[j] = i1[j]; v1[j] = part; i1[j] = row; }
        else if (part > v2[j]) { v2[j] = part; i2[j] = row; }
      }
    }
  }

#pragma unroll
  for (int j = 0; j < 4; ++j) {
#pragma unroll
    for (int m = 1; m < 64; m <<= 1) {  // butterfly merge (desc value, low index on ties)
      const float u0 = __shfl_xor(v0[j], m);
      const float u1 = __shfl_xor(v1[j], m);
      const float u2 = __shfl_xor(v2[j], m);
      const int j0 = __shfl_xor(i0[j], m);
      const int j1 = __shfl_xor(i1[j], m);
      const int j2 = __shfl_xor(i2[j], m);
#pragma unroll
      for (int t = 0; t < 3; ++t) {
        const float u = (t == 0) ? u0 : (t == 1) ? u1 : u2;
        const int jj = (t == 0) ? j0 : (t == 1) ? j1 : j2;
        const bool b0 = (u > v0[j]) || (u == v0[j] && jj < i0[j]);
        const bool b1 = (u > v1[j]) || (u == v1[j] && jj < i1[j]);
        const bool b2 = (u > v2[j]) || (u == v2[j] && jj < i2[j]);
        if (b0) { v2[j] = v1[j]; i2[j] = i1[j]; v1[j] = v0[j]; i1[j] = i0[j]; v0[j] = u; i0[j] = jj; }
        else if (b1) { v2[j] = v1[j]; i2[j] = i1[j]; v1[j] = u; i1[j] = jj; }
        else if (b2) { v2[j] = u; i2[j] = jj; }
      }
    }
    const float e1 = __expf(v1[j] - v0[j]);
    const float e2 = __expf(v2[j] - v0[j]);
    const float inv = 1.f / (1.f + e1 + e2);
    if (lane < D) {
      const float* Cl = C + l * S * D;
      out[(t0 + j) * D + lane] = inv * Cl[i0[j] * D + lane] +
                                 e1 * inv * Cl[i1[j] * D + lane] +
                                 e2 * inv * Cl[i2[j] * D + lane];
    }
  }
}

}  // namespace

extern "C" void kernel_launch(void* const* d_in, const int* in_sizes, int n_in,
                              void* d_out, int out_size, void* d_ws, size_t ws_size,
                              hipStream_t stream) {
  const float* x = (const float*)d_in[0];      // [L,B,D]
  const float* vc = (const float*)d_in[1];     // [L,S,D]
  const float* vec = (const float*)d_in[2];    // [L,S,SE,D]
  const float* gain = (const float*)d_in[3];   // [L,S,SE,2]
  const int* blk = (const int*)d_in[4];        // [L,S,SE,2]
  float* out = (float*)d_out;                  // [L,B,D]
  float* C = (float*)d_ws;                     // L*S*D floats = 179,200 B

  compose_kernel<<<NCLUST, 64, 0, stream>>>(vec, gain, blk, C);
  route_kernel<<<NTOK / 16, 256, 0, stream>>>(x, vc, C, out);
}

// Round 8
// 27.612 us; speedup vs baseline: 5.5075x; 2.4839x over previous
//
#include <hip/hip_runtime.h>
#include <math.h>

namespace {
constexpr int L = 7, S = 200, SE = 240, D = 32, B = 512;
constexpr int NTOK = L * B;      // 3584
constexpr int NCLUST = L * S;    // 1400

// ---- cross-lane helpers: DPP (VALU-speed) where possible, DS only for xor16 ----
template <int CTRL>
__device__ __forceinline__ float dppf(float x) {  // value from lane per DPP ctrl
  return __int_as_float(__builtin_amdgcn_update_dpp(
      0, __float_as_int(x), CTRL, 0xF, 0xF, true));
}
template <int CTRL>
__device__ __forceinline__ int dppi(int x) {
  return __builtin_amdgcn_update_dpp(0, x, CTRL, 0xF, 0xF, true);
}
// DPP ctrl codes: quad_perm[1,0,3,2]=0xB1 (xor1), quad_perm[2,3,0,1]=0x4E (xor2),
// row_half_mirror=0x141 (lane^7 within 16), row_ror:8=0x128 (lane^8 within 16).
__device__ __forceinline__ float swz16f(float x) {  // lane^16 (ds_swizzle, within 32)
  return __int_as_float(__builtin_amdgcn_ds_swizzle(__float_as_int(x), 0x401F));
}
__device__ __forceinline__ int swz16i(int x) {
  return __builtin_amdgcn_ds_swizzle(x, 0x401F);
}

// ---------- kernel 1: compose. One WAVE per cluster, 1400 one-wave blocks. ----------
// C[ls,d] = sum_e sigmoid(gain[ls,e,0]) * (blk[ls,e,0]!=0) * vec[ls,e,d]
__global__ __launch_bounds__(64) void compose_kernel(
    const float* __restrict__ vec,   // [L,S,SE,D]
    const float* __restrict__ gain,  // [L,S,SE,2]
    const int* __restrict__ blk,     // [L,S,SE,2]
    float* __restrict__ C)           // [L*S, D]
{
  const int ls = blockIdx.x;
  const int lane = threadIdx.x;
  __shared__ float sw[SE];
  for (int e = lane; e < SE; e += 64) {
    const float2 g2 = reinterpret_cast<const float2*>(gain)[ls * SE + e];  // coalesced 8B
    const int2 b2 = reinterpret_cast<const int2*>(blk)[ls * SE + e];
    sw[e] = (b2.x != 0) ? 1.0f / (1.0f + __expf(-g2.x)) : 0.0f;
  }
  __syncthreads();
  const int d4 = lane & 7;   // float4 column [0,8)
  const int eg = lane >> 3;  // e-row group [0,8)
  const float4* v4 = reinterpret_cast<const float4*>(vec) + (size_t)ls * SE * 8;
  float4 acc = make_float4(0.f, 0.f, 0.f, 0.f);
#pragma unroll 10
  for (int k = 0; k < 30; ++k) {  // wave reads 8 rows x 128B = 1KB contiguous per step
    const int e = eg + 8 * k;
    const float we = sw[e];
    const float4 v = v4[e * 8 + d4];
    acc.x += we * v.x; acc.y += we * v.y; acc.z += we * v.z; acc.w += we * v.w;
  }
  // reduce over eg (lane bits 3,4,5): xor8 via DPP, xor16 via swizzle, xor32 via shfl
  acc.x += dppf<0x128>(acc.x); acc.y += dppf<0x128>(acc.y);
  acc.z += dppf<0x128>(acc.z); acc.w += dppf<0x128>(acc.w);
  acc.x += swz16f(acc.x); acc.y += swz16f(acc.y);
  acc.z += swz16f(acc.z); acc.w += swz16f(acc.w);
  acc.x += __shfl_xor(acc.x, 32); acc.y += __shfl_xor(acc.y, 32);
  acc.z += __shfl_xor(acc.z, 32); acc.w += __shfl_xor(acc.w, 32);
  if (eg == 0) reinterpret_cast<float4*>(C + ls * D)[d4] = acc;
}

// ---------- kernel 2: route + gather. ONE token per wave, 3584 waves. ----------
// Per chunk of 8 rows: coalesced float4 load, 4 FMA, 3 DPP adds (octet reduce,
// zero DS ops) -> every lane holds the dot for its octet's row; all lanes run the
// top-3 insert (no divergence). Merge needs only 3 steps (octets differ in lane
// bits 3,4,5): xor8 (DPP), xor16 (1 swizzle/component), xor32 (shfl).
__global__ __launch_bounds__(256) void route_kernel(
    const float* __restrict__ x,   // [L,B,D]
    const float* __restrict__ vc,  // [L,S,D]
    const float* __restrict__ C,   // [L*S, D]
    float* __restrict__ out)       // [L,B,D]
{
  const int wave = threadIdx.x >> 6;
  const int lane = threadIdx.x & 63;
  const int tok = blockIdx.x * 4 + wave;  // grid 896 * 4 waves = 3584
  const int l = tok >> 9;                 // B = 512
  const int q = lane & 7;
  const int r8 = lane >> 3;

  const float4 xq = reinterpret_cast<const float4*>(x + tok * D)[q];  // one 128B line
  const float* vcl = vc + l * S * D;

  float v0 = -INFINITY, v1 = -INFINITY, v2 = -INFINITY;
  int i0 = 0x7fffffff, i1 = 0x7fffffff, i2 = 0x7fffffff;
  for (int s0 = 0; s0 < S; s0 += 8) {  // 25 chunks; wave reads 8 rows x 128B contiguous
    const int row = s0 + r8;
    const float4 v = reinterpret_cast<const float4*>(vcl + row * D)[q];
    float part = v.x * xq.x + v.y * xq.y + v.z * xq.z + v.w * xq.w;
    part += dppf<0xB1>(part);   // xor1 (quad_perm)
    part += dppf<0x4E>(part);   // xor2 (quad_perm)
    part += dppf<0x141>(part);  // half_mirror: other quad of same octet (quads uniform)
    // all 8 lanes of octet r8 now hold the full dot for `row`; insert on all lanes
    if (part > v0) { v2 = v1; i2 = i1; v1 = v0; i1 = i0; v0 = part; i0 = row; }
    else if (part > v1) { v2 = v1; i2 = i1; v1 = part; i1 = row; }
    else if (part > v2) { v2 = part; i2 = row; }
  }

  // 3-step merge across octets (partners always hold disjoint row residues)
#pragma unroll
  for (int step = 0; step < 3; ++step) {
    float u0, u1, u2; int j0, j1, j2;
    if (step == 0) {        // xor8: DPP row_ror:8 (VALU)
      u0 = dppf<0x128>(v0); u1 = dppf<0x128>(v1); u2 = dppf<0x128>(v2);
      j0 = dppi<0x128>(i0); j1 = dppi<0x128>(i1); j2 = dppi<0x128>(i2);
    } else if (step == 1) { // xor16: ds_swizzle
      u0 = swz16f(v0); u1 = swz16f(v1); u2 = swz16f(v2);
      j0 = swz16i(i0); j1 = swz16i(i1); j2 = swz16i(i2);
    } else {                // xor32
      u0 = __shfl_xor(v0, 32); u1 = __shfl_xor(v1, 32); u2 = __shfl_xor(v2, 32);
      j0 = __shfl_xor(i0, 32); j1 = __shfl_xor(i1, 32); j2 = __shfl_xor(i2, 32);
    }
#pragma unroll
    for (int t = 0; t < 3; ++t) {  // jax tie-break: desc value, lower index on ties
      const float u = (t == 0) ? u0 : (t == 1) ? u1 : u2;
      const int j = (t == 0) ? j0 : (t == 1) ? j1 : j2;
      const bool b0 = (u > v0) || (u == v0 && j < i0);
      const bool b1 = (u > v1) || (u == v1 && j < i1);
      const bool b2 = (u > v2) || (u == v2 && j < i2);
      if (b0) { v2 = v1; i2 = i1; v1 = v0; i1 = i0; v0 = u; i0 = j; }
      else if (b1) { v2 = v1; i2 = i1; v1 = u; i1 = j; }
      else if (b2) { v2 = u; i2 = j; }
    }
  }

  const float e1 = __expf(v1 - v0);
  const float e2 = __expf(v2 - v0);
  const float inv = 1.f / (1.f + e1 + e2);

  if (lane < D) {
    const float* Cl = C + l * S * D;
    out[tok * D + lane] = inv * Cl[i0 * D + lane] +
                          e1 * inv * Cl[i1 * D + lane] +
                          e2 * inv * Cl[i2 * D + lane];
  }
}

}  // namespace

extern "C" void kernel_launch(void* const* d_in, const int* in_sizes, int n_in,
                              void* d_out, int out_size, void* d_ws, size_t ws_size,
                              hipStream_t stream) {
  const float* x = (const float*)d_in[0];      // [L,B,D]
  const float* vc = (const float*)d_in[1];     // [L,S,D]
  const float* vec = (const float*)d_in[2];    // [L,S,SE,D]
  const float* gain = (const float*)d_in[3];   // [L,S,SE,2]
  const int* blk = (const int*)d_in[4];        // [L,S,SE,2]
  float* out = (float*)d_out;                  // [L,B,D]
  float* C = (float*)d_ws;                     // L*S*D floats = 179,200 B

  compose_kernel<<<NCLUST, 64, 0, stream>>>(vec, gain, blk, C);
  route_kernel<<<NTOK / 4, 256, 0, stream>>>(x, vc, C, out);
}

// Round 9
// 23.465 us; speedup vs baseline: 6.4809x; 1.1767x over previous
//
#include <hip/hip_runtime.h>
#include <math.h>

namespace {
constexpr int L = 7, S = 200, SE = 240, D = 32, B = 512;
constexpr int NTOK = L * B;              // 3584
constexpr int NCLUST = L * S;            // 1400
constexpr int NCOMP_BLK = NCLUST / 4;    // 350 compose blocks (wave-per-cluster)
constexpr int NROUTE_BLK = NTOK / 4;     // 896 route-A blocks (wave-per-token)
constexpr int GRID1 = NCOMP_BLK + NROUTE_BLK;  // 1246

// ---- cross-lane helpers: DPP (VALU-speed), DS only for xor16 (proven in R8) ----
template <int CTRL>
__device__ __forceinline__ float dppf(float x) {
  return __int_as_float(__builtin_amdgcn_update_dpp(
      0, __float_as_int(x), CTRL, 0xF, 0xF, true));
}
template <int CTRL>
__device__ __forceinline__ int dppi(int x) {
  return __builtin_amdgcn_update_dpp(0, x, CTRL, 0xF, 0xF, true);
}
// quad_perm[1,0,3,2]=0xB1 (xor1), quad_perm[2,3,0,1]=0x4E (xor2),
// row_half_mirror=0x141 (lane^7 in 16 => other quad), row_ror:8=0x128 (lane^8 in 16).
__device__ __forceinline__ float swz16f(float x) {  // lane^16 (within 32)
  return __int_as_float(__builtin_amdgcn_ds_swizzle(__float_as_int(x), 0x401F));
}
__device__ __forceinline__ int swz16i(int x) {
  return __builtin_amdgcn_ds_swizzle(x, 0x401F);
}

// ---------------- node 1: compose (350 blocks) || route-A (896 blocks) ----------------
// Compose: C[ls,d] = sum_e sigmoid(gain[ls,e,0])*(blk[ls,e,0]!=0)*vec[ls,e,d].
// Route-A: per token, 200 dots vs centroids, exact top-3 (jax tie-break: desc value,
// lower index), softmax -> (tki, tkp). Route-A reads neither C nor vec: no dependency
// inside this dispatch; it fills CU slots compose leaves idle.
__global__ __launch_bounds__(256) void fused1_kernel(
    const float* __restrict__ x,     // [L,B,D]
    const float* __restrict__ vc,    // [L,S,D]
    const float* __restrict__ vec,   // [L,S,SE,D]
    const float* __restrict__ gain,  // [L,S,SE,2]
    const int* __restrict__ blk,     // [L,S,SE,2]
    float* __restrict__ C,           // [L*S, D] ws
    int4* __restrict__ tki,          // [NTOK] ws
    float4* __restrict__ tkp)        // [NTOK] ws
{
  const int wave = threadIdx.x >> 6;
  const int lane = threadIdx.x & 63;

  if (blockIdx.x < NCOMP_BLK) {
    // ---- compose: one wave per (l,s); dispatched first = starts streaming ASAP ----
    __shared__ float wl[4][SE];
    const int ls = blockIdx.x * 4 + wave;
    for (int e = lane; e < SE; e += 64) {
      const float2 g2 = reinterpret_cast<const float2*>(gain)[ls * SE + e];  // 8B coalesced
      const int2 b2 = reinterpret_cast<const int2*>(blk)[ls * SE + e];
      wl[wave][e] = (b2.x != 0) ? 1.0f / (1.0f + __expf(-g2.x)) : 0.0f;
    }
    __syncthreads();  // uniform across the 4 compose waves of this block
    const int d4 = lane & 7;   // float4 column [0,8)
    const int eg = lane >> 3;  // e-row group [0,8)
    const float4* v4 = reinterpret_cast<const float4*>(vec) + (size_t)ls * SE * 8;
    float4 acc = make_float4(0.f, 0.f, 0.f, 0.f);
#pragma unroll 10
    for (int k = 0; k < 30; ++k) {  // wave reads 8 rows x 128B = 1KB contiguous per step
      const int e = eg + 8 * k;
      const float we = wl[wave][e];
      const float4 v = v4[e * 8 + d4];
      acc.x += we * v.x; acc.y += we * v.y; acc.z += we * v.z; acc.w += we * v.w;
    }
    // reduce over eg (lane bits 3,4,5): xor8 DPP, xor16 swizzle, xor32 shfl (R8-proven)
    acc.x += dppf<0x128>(acc.x); acc.y += dppf<0x128>(acc.y);
    acc.z += dppf<0x128>(acc.z); acc.w += dppf<0x128>(acc.w);
    acc.x += swz16f(acc.x); acc.y += swz16f(acc.y);
    acc.z += swz16f(acc.z); acc.w += swz16f(acc.w);
    acc.x += __shfl_xor(acc.x, 32); acc.y += __shfl_xor(acc.y, 32);
    acc.z += __shfl_xor(acc.z, 32); acc.w += __shfl_xor(acc.w, 32);
    if (eg == 0) reinterpret_cast<float4*>(C + ls * D)[d4] = acc;
  } else {
    // ---- route-A: one token per wave (R8-proven DPP path) ----
    const int tok = (blockIdx.x - NCOMP_BLK) * 4 + wave;
    const int l = tok >> 9;  // B = 512
    const int q = lane & 7;
    const int r8 = lane >> 3;

    const float4 xq = reinterpret_cast<const float4*>(x + tok * D)[q];  // one 128B line
    const float* vcl = vc + l * S * D;

    float v0 = -INFINITY, v1 = -INFINITY, v2 = -INFINITY;
    int i0 = 0x7fffffff, i1 = 0x7fffffff, i2 = 0x7fffffff;
    for (int s0 = 0; s0 < S; s0 += 8) {  // 25 chunks; 8 rows x 128B contiguous per wave
      const int row = s0 + r8;
      const float4 v = reinterpret_cast<const float4*>(vcl + row * D)[q];
      float part = v.x * xq.x + v.y * xq.y + v.z * xq.z + v.w * xq.w;
      part += dppf<0xB1>(part);   // xor1
      part += dppf<0x4E>(part);   // xor2
      part += dppf<0x141>(part);  // other quad of octet (quads uniform after xor1/2)
      // all 8 lanes of octet r8 hold the dot for `row`; insert on all lanes
      if (part > v0) { v2 = v1; i2 = i1; v1 = v0; i1 = i0; v0 = part; i0 = row; }
      else if (part > v1) { v2 = v1; i2 = i1; v1 = part; i1 = row; }
      else if (part > v2) { v2 = part; i2 = row; }
    }
    // 3-step merge across octets (partners hold disjoint row residues)
#pragma unroll
    for (int step = 0; step < 3; ++step) {
      float u0, u1, u2; int j0, j1, j2;
      if (step == 0) {
        u0 = dppf<0x128>(v0); u1 = dppf<0x128>(v1); u2 = dppf<0x128>(v2);
        j0 = dppi<0x128>(i0); j1 = dppi<0x128>(i1); j2 = dppi<0x128>(i2);
      } else if (step == 1) {
        u0 = swz16f(v0); u1 = swz16f(v1); u2 = swz16f(v2);
        j0 = swz16i(i0); j1 = swz16i(i1); j2 = swz16i(i2);
      } else {
        u0 = __shfl_xor(v0, 32); u1 = __shfl_xor(v1, 32); u2 = __shfl_xor(v2, 32);
        j0 = __shfl_xor(i0, 32); j1 = __shfl_xor(i1, 32); j2 = __shfl_xor(i2, 32);
      }
#pragma unroll
      for (int t = 0; t < 3; ++t) {  // jax tie-break: desc value, lower index
        const float u = (t == 0) ? u0 : (t == 1) ? u1 : u2;
        const int j = (t == 0) ? j0 : (t == 1) ? j1 : j2;
        const bool b0 = (u > v0) || (u == v0 && j < i0);
        const bool b1 = (u > v1) || (u == v1 && j < i1);
        const bool b2 = (u > v2) || (u == v2 && j < i2);
        if (b0) { v2 = v1; i2 = i1; v1 = v0; i1 = i0; v0 = u; i0 = j; }
        else if (b1) { v2 = v1; i2 = i1; v1 = u; i1 = j; }
        else if (b2) { v2 = u; i2 = j; }
      }
    }
    if (lane == 0) {
      const float e1 = __expf(v1 - v0);
      const float e2 = __expf(v2 - v0);
      const float inv = 1.f / (1.f + e1 + e2);
      tki[tok] = make_int4(i0, i1, i2, 0);
      tkp[tok] = make_float4(inv, e1 * inv, e2 * inv, 0.f);
    }
  }
}

// ---------------- node 2: gather. Thread per (token, d). ----------------
// tki/tkp uniform per 32-thread token-group -> broadcast loads; C rows 128B
// contiguous, L2-hot (C = 180KB total); out fully coalesced.
__global__ __launch_bounds__(256) void gather_kernel(
    const float* __restrict__ C,      // [L*S, D]
    const int4* __restrict__ tki,     // [NTOK]
    const float4* __restrict__ tkp,   // [NTOK]
    float* __restrict__ out)          // [L,B,D]
{
  const int gid = blockIdx.x * 256 + threadIdx.x;  // 448 blocks * 256 = NTOK*D
  const int tok = gid >> 5;
  const int d = gid & 31;
  const int l = tok >> 9;
  const int4 id = tki[tok];
  const float4 p = tkp[tok];
  const float* Cl = C + l * S * D;
  out[gid] = p.x * Cl[id.x * D + d] + p.y * Cl[id.y * D + d] + p.z * Cl[id.z * D + d];
}

}  // namespace

extern "C" void kernel_launch(void* const* d_in, const int* in_sizes, int n_in,
                              void* d_out, int out_size, void* d_ws, size_t ws_size,
                              hipStream_t stream) {
  const float* x = (const float*)d_in[0];      // [L,B,D]
  const float* vc = (const float*)d_in[1];     // [L,S,D]
  const float* vec = (const float*)d_in[2];    // [L,S,SE,D]
  const float* gain = (const float*)d_in[3];   // [L,S,SE,2]
  const int* blk = (const int*)d_in[4];        // [L,S,SE,2]
  float* out = (float*)d_out;                  // [L,B,D]

  char* ws = (char*)d_ws;
  float* C = (float*)ws;                          // 179,200 B
  int4* tki = (int4*)(ws + 179200);               // 57,344 B (16B aligned)
  float4* tkp = (float4*)(ws + 179200 + 57344);   // 57,344 B

  fused1_kernel<<<GRID1, 256, 0, stream>>>(x, vc, vec, gain, blk, C, tki, tkp);
  gather_kernel<<<NTOK * D / 256, 256, 0, stream>>>(C, tki, tkp, out);
}